// Round 2
// baseline (3793.413 us; speedup 1.0000x reference)
//
#include <hip/hip_runtime.h>
#include <hip/hip_bf16.h>
#include <math.h>

typedef __bf16 bf16;
typedef __bf16 bf16x4 __attribute__((ext_vector_type(4)));
typedef __bf16 bf16x8 __attribute__((ext_vector_type(8)));
typedef float f32x4 __attribute__((ext_vector_type(4)));

#define BB 64
#define NN 49
#define CENC 2048
#define SS 26
#define NSTEP 25
#define VV 10000
#define EE 512
#define HH 512
#define AAT 512
#define ALPHA_OFF (BB*NSTEP*VV)   /* 16,000,000 */

// ~76 MiB workspace; everything written before read within one launch sequence.
struct Wks {
  float att1[BB*NN*AAT];        // fp32, loop-invariant attention projection
  float h[2][BB*HH];            // double-buffered fp32 LSTM state
  float c[2][BB*HH];
  bf16 h_hi[2][BB*HH];          // hi/lo bf16 split of h for MFMA operands
  bf16 h_lo[2][BB*HH];
  bf16 ctx_hi[BB*CENC];         // hi/lo split of attention context
  bf16 ctx_lo[BB*CENC];
  bf16 mean_hi[BB*CENC];        // hi/lo split of mean-pooled encoder features
  bf16 mean_lo[BB*CENC];
  bf16 feat_hi[BB*NN*CENC];     // hi/lo split of features (A operand of att1)
  bf16 feat_lo[BB*NN*CENC];
  bf16 Wih_hi[4*HH*(EE+CENC)];  // hi/lo: recurrent-path weights (3-term accuracy)
  bf16 Wih_lo[4*HH*(EE+CENC)];
  bf16 Whh_hi[4*HH*HH];
  bf16 Whh_lo[4*HH*HH];
  bf16 Wenc_hi[AAT*CENC];       // hi only (2-term)
  bf16 Wfcn_hi[VV*HH];          // hi only (2-term)
  bf16 Winh_hi[HH*CENC];        // hi only
  bf16 Winc_hi[HH*CENC];        // hi only
};

__device__ inline bf16x8 ldb8(const bf16* p){ return *(const bf16x8*)p; }
__device__ inline f32x4 mfma16(bf16x8 a, bf16x8 b, f32x4 c){
  return __builtin_amdgcn_mfma_f32_16x16x32_bf16(a, b, c, 0, 0, 0);
}
__device__ inline float sigm(float x){ return 1.0f/(1.0f+expf(-x)); }

// split 8 consecutive fp32 into bf16 hi + lo fragments (register-level)
__device__ inline void split8(const float* p, bf16x8& hi, bf16x8& lo){
  float4 v0 = *(const float4*)p;
  float4 v1 = *(const float4*)(p+4);
  float v[8] = {v0.x,v0.y,v0.z,v0.w,v1.x,v1.y,v1.z,v1.w};
  #pragma unroll
  for (int j=0;j<8;j++){ bf16 h=(bf16)v[j]; hi[j]=h; lo[j]=(bf16)(v[j]-(float)h); }
}

// ---------------- fp32 -> bf16 hi (+ optional lo) elementwise convert --------------
__global__ __launch_bounds__(256) void k_cvt(const float* __restrict__ src,
    bf16* __restrict__ hi, bf16* __restrict__ lo, int n4){
  int i = blockIdx.x*256 + threadIdx.x;
  if (i >= n4) return;
  float4 v = ((const float4*)src)[i];
  float a[4] = {v.x, v.y, v.z, v.w};
  bf16x4 hv, lv;
  #pragma unroll
  for (int j=0;j<4;j++){ bf16 h=(bf16)a[j]; hv[j]=h; lv[j]=(bf16)(a[j]-(float)h); }
  *(bf16x4*)(hi + i*4) = hv;
  if (lo) *(bf16x4*)(lo + i*4) = lv;
}

// ---------------- mean over N=49 feature pixels, split into bf16 hi/lo -------------
__global__ __launch_bounds__(256) void k_mean(const float* __restrict__ feat, Wks* __restrict__ ws){
  int idx = blockIdx.x*256 + threadIdx.x;      // 64*2048 = 131072 total
  int b = idx >> 11, ch = idx & 2047;
  const float* p = feat + (size_t)b*NN*CENC + ch;
  float s = 0.f;
  #pragma unroll
  for (int n=0;n<NN;n++) s += p[n*CENC];
  s *= (1.0f/49.0f);
  bf16 hi = (bf16)s;
  ws->mean_hi[idx] = hi;
  ws->mean_lo[idx] = (bf16)(s - (float)hi);
}

// ---------------- h0 = mean @ W_init_h^T + b ; c0 likewise (2-term hi/lo) ----------
__global__ __launch_bounds__(256) void k_init(Wks* __restrict__ ws,
    const float* __restrict__ bh, const float* __restrict__ bc){
  int wid = threadIdx.x >> 6, lane = threadIdx.x & 63;
  int w = blockIdx.x*4 + wid;                  // 0..63
  int mat = w >> 5, nt = w & 31;
  int lane15 = lane & 15, quad = lane >> 4, koff = quad*8;
  const bf16* Wm = mat ? ws->Winc_hi : ws->Winh_hi;
  const float* bm = mat ? bc : bh;
  int col = nt*16 + lane15;
  const bf16* brow = Wm + (size_t)col*CENC;
  f32x4 acc[4] = {};
  for (int kk=0; kk<CENC; kk+=32){
    bf16x8 bfr = ldb8(brow + kk + koff);
    #pragma unroll
    for (int t=0;t<4;t++){
      acc[t] = mfma16(ldb8(ws->mean_hi + (t*16+lane15)*CENC + kk + koff), bfr, acc[t]);
      acc[t] = mfma16(ldb8(ws->mean_lo + (t*16+lane15)*CENC + kk + koff), bfr, acc[t]);
    }
  }
  float bias = bm[col];
  #pragma unroll
  for (int t=0;t<4;t++){
    #pragma unroll
    for (int r=0;r<4;r++){
      int b = t*16 + quad*4 + r;
      float v = acc[t][r] + bias;
      if (mat == 0){
        ws->h[0][b*HH + col] = v;
        bf16 hi = (bf16)v;
        ws->h_hi[0][b*HH+col] = hi;
        ws->h_lo[0][b*HH+col] = (bf16)(v - (float)hi);
      } else {
        ws->c[0][b*HH + col] = v;
      }
    }
  }
}

// ---------------- att1 = features @ W_enc_att^T + b (2-term hi/lo, fp32 out) -------
__global__ __launch_bounds__(256) void k_att1(const float* __restrict__ benc, Wks* __restrict__ ws){
  int wid = threadIdx.x>>6, lane = threadIdx.x&63;
  int w = blockIdx.x*4 + wid;                  // 0..1567 : 196 m-tiles x 8 n-groups
  int mt = w >> 3, ng = w & 7;
  int lane15 = lane&15, quad = lane>>4, koff = quad*8;
  const bf16* ah = ws->feat_hi + (size_t)(mt*16 + lane15)*CENC;
  const bf16* al = ws->feat_lo + (size_t)(mt*16 + lane15)*CENC;
  int a0 = ng*64;
  f32x4 acc[4] = {};
  for (int kk=0; kk<CENC; kk+=32){
    bf16x8 fh = ldb8(ah + kk + koff);
    bf16x8 fl = ldb8(al + kk + koff);
    #pragma unroll
    for (int u=0;u<4;u++){
      bf16x8 wv = ldb8(ws->Wenc_hi + (size_t)(a0+u*16+lane15)*CENC + kk + koff);
      acc[u] = mfma16(fh, wv, acc[u]);
      acc[u] = mfma16(fl, wv, acc[u]);
    }
  }
  #pragma unroll
  for (int u=0;u<4;u++){
    int colb = a0 + u*16 + lane15;
    float bias = benc[colb];
    #pragma unroll
    for (int r=0;r<4;r++){
      int row = mt*16 + quad*4 + r;
      ws->att1[(size_t)row*AAT + colb] = acc[u][r] + bias;
    }
  }
}

// ---------------- per-step kernel A: attention(t) [blocks 0..63] + pred(t-1) -------
__global__ __launch_bounds__(256) void k_step_a(
    int t, int par, int do_att, int do_pred, int pred_s,
    const float* __restrict__ feat,
    const float* __restrict__ Wdec, const float* __restrict__ bdec,
    const float* __restrict__ Wfull, const float* __restrict__ bfull,
    const float* __restrict__ bfcn,
    Wks* __restrict__ ws, float* __restrict__ out)
{
  int tid = threadIdx.x;
  int wid = tid>>6, lane = tid&63;
  if (blockIdx.x < 64){
    if (!do_att) return;
    int b = blockIdx.x;
    __shared__ float sh_att2[512];
    __shared__ float sh_wf[512];
    __shared__ float sh_alpha[64];
    __shared__ float sh_e[64];
    // h for this b: 8 fp32 per lane, register-resident (full 512 across the wave)
    float hreg[8];
    const float* hp = ws->h[par] + b*HH;
    #pragma unroll
    for (int j=0;j<8;j++) hreg[j] = hp[lane*8 + j];
    for (int i=tid; i<512; i+=256) sh_wf[i] = Wfull[i];
    // att2[a] = h . Wdec[a,:] + bdec[a]  -- coalesced row loads + 64-lane reduce
    for (int a = wid; a < 512; a += 4){
      const float* wr = Wdec + (size_t)a*HH + lane*8;
      float4 w0 = *(const float4*)wr;
      float4 w1 = *(const float4*)(wr+4);
      float wv[8] = {w0.x,w0.y,w0.z,w0.w,w1.x,w1.y,w1.z,w1.w};
      float s = 0.f;
      #pragma unroll
      for (int j=0;j<8;j++) s += wv[j]*hreg[j];
      #pragma unroll
      for (int off=32; off; off>>=1) s += __shfl_xor(s, off, 64);
      if (lane==0) sh_att2[a] = s + bdec[a];
    }
    __syncthreads();
    // e[n] = relu(att1 + att2) . w_full + b_full
    for (int n = wid; n < NN; n += 4){
      const float* at1 = ws->att1 + (size_t)(b*NN + n)*AAT + lane*8;
      const float* a2  = sh_att2 + lane*8;
      const float* wf  = sh_wf + lane*8;
      float s = 0.f;
      #pragma unroll
      for (int j=0;j<8;j++){
        float v = at1[j] + a2[j];
        v = fmaxf(v, 0.0f);
        s += v * wf[j];
      }
      #pragma unroll
      for (int off=32; off; off>>=1) s += __shfl_xor(s, off, 64);
      if (lane==0) sh_e[n] = s + bfull[0];
    }
    __syncthreads();
    if (wid == 0){
      float e = (lane < NN) ? sh_e[lane] : -1e30f;
      float m = e;
      #pragma unroll
      for (int off=32; off; off>>=1) m = fmaxf(m, __shfl_xor(m, off, 64));
      float p = (lane < NN) ? expf(e - m) : 0.0f;
      float sum = p;
      #pragma unroll
      for (int off=32; off; off>>=1) sum += __shfl_xor(sum, off, 64);
      float al = p / sum;
      if (lane < NN){
        sh_alpha[lane] = al;
        out[ALPHA_OFF + (size_t)(b*NSTEP + t)*NN + lane] = al;
      }
    }
    __syncthreads();
    // context[ch] = sum_n alpha[n] * feat[b,n,ch]; write hi/lo split (fp32 exact sum)
    int ch0 = tid*8;
    float acc[8] = {};
    for (int n=0;n<NN;n++){
      float al = sh_alpha[n];
      const float* fp = feat + (size_t)(b*NN+n)*CENC + ch0;
      float4 f0 = *(const float4*)fp;
      float4 f1 = *(const float4*)(fp+4);
      float fv[8] = {f0.x,f0.y,f0.z,f0.w,f1.x,f1.y,f1.z,f1.w};
      #pragma unroll
      for (int j=0;j<8;j++) acc[j] += al*fv[j];
    }
    #pragma unroll
    for (int j=0;j<8;j++){
      float v = acc[j];
      bf16 hi = (bf16)v;
      ws->ctx_hi[b*CENC + ch0 + j] = hi;
      ws->ctx_lo[b*CENC + ch0 + j] = (bf16)(v - (float)hi);
    }
  } else {
    if (!do_pred) return;
    int wi = (blockIdx.x - 64)*4 + wid;        // 0..627, 625 used (10000/16)
    if (wi >= 625) return;
    int lane15 = lane&15, quad = lane>>4, koff = quad*8;
    int v0 = wi*16 + lane15;
    const bf16* brow = ws->Wfcn_hi + (size_t)v0*HH;
    const bf16* hh = ws->h_hi[par];
    const bf16* hl = ws->h_lo[par];
    f32x4 acc[4] = {};
    for (int kk=0; kk<HH; kk+=32){
      bf16x8 bfr = ldb8(brow + kk + koff);
      #pragma unroll
      for (int t4=0;t4<4;t4++){
        acc[t4] = mfma16(ldb8(hh + (t4*16+lane15)*HH + kk + koff), bfr, acc[t4]);
        acc[t4] = mfma16(ldb8(hl + (t4*16+lane15)*HH + kk + koff), bfr, acc[t4]);
      }
    }
    float bias = bfcn[v0];
    #pragma unroll
    for (int t4=0;t4<4;t4++){
      #pragma unroll
      for (int r=0;r<4;r++){
        int bb2 = t4*16 + quad*4 + r;
        out[(size_t)(bb2*NSTEP + pred_s)*VV + v0] = acc[t4][r] + bias;
      }
    }
  }
}

// ---------------- per-step kernel B: gates GEMM (3-term hi/lo) + LSTM epilogue -----
__global__ __launch_bounds__(256) void k_step_b(
    int s, int par,
    const int* __restrict__ caps, const float* __restrict__ emb,
    const float* __restrict__ bih, const float* __restrict__ bhh,
    Wks* __restrict__ ws)
{
  int tid = threadIdx.x;
  int g = tid>>6, lane = tid&63;               // wave = gate (i,f,g,o)
  int bt = blockIdx.x >> 5, jt = blockIdx.x & 31;
  int lane15 = lane&15, quad = lane>>4, koff = quad*8;
  int j = g*HH + jt*16 + lane15;               // row of W_ih / W_hh
  const bf16* wih_hi = ws->Wih_hi + (size_t)j*(EE+CENC);
  const bf16* wih_lo = ws->Wih_lo + (size_t)j*(EE+CENC);
  const bf16* whh_hi = ws->Whh_hi + (size_t)j*HH;
  const bf16* whh_lo = ws->Whh_lo + (size_t)j*HH;
  int brow = bt*16 + lane15;                   // batch row for A operand
  int cap = caps[brow*SS + s];
  const float* aemb = emb + (size_t)cap*EE;
  const bf16* achi = ws->ctx_hi + brow*CENC;
  const bf16* aclo = ws->ctx_lo + brow*CENC;
  const bf16* ahhi = ws->h_hi[par] + brow*HH;
  const bf16* ahlo = ws->h_lo[par] + brow*HH;
  f32x4 acc = {};
  for (int kk=0; kk<EE; kk+=32){               // embedding: on-the-fly hi/lo split
    bf16x8 ah, al;
    split8(aemb + kk + koff, ah, al);
    bf16x8 whi = ldb8(wih_hi + kk + koff);
    bf16x8 wlo = ldb8(wih_lo + kk + koff);
    acc = mfma16(ah, whi, acc);
    acc = mfma16(al, whi, acc);
    acc = mfma16(ah, wlo, acc);
  }
  for (int kk=0; kk<CENC; kk+=32){             // context
    bf16x8 whi = ldb8(wih_hi + EE + kk + koff);
    bf16x8 wlo = ldb8(wih_lo + EE + kk + koff);
    bf16x8 ah = ldb8(achi + kk + koff);
    acc = mfma16(ah, whi, acc);
    acc = mfma16(ldb8(aclo + kk + koff), whi, acc);
    acc = mfma16(ah, wlo, acc);
  }
  for (int kk=0; kk<HH; kk+=32){               // recurrent h
    bf16x8 whi = ldb8(whh_hi + kk + koff);
    bf16x8 wlo = ldb8(whh_lo + kk + koff);
    bf16x8 ah = ldb8(ahhi + kk + koff);
    acc = mfma16(ah, whi, acc);
    acc = mfma16(ldb8(ahlo + kk + koff), whi, acc);
    acc = mfma16(ah, wlo, acc);
  }
  float bias = bih[j] + bhh[j];
  __shared__ float sg[4][16][16];
  #pragma unroll
  for (int r=0;r<4;r++) sg[g][quad*4+r][lane15] = acc[r] + bias;
  __syncthreads();
  int row = tid>>4, col = tid&15;
  int b2 = bt*16 + row, jj = jt*16 + col;
  float iv = sg[0][row][col], fv = sg[1][row][col], gv = sg[2][row][col], ov = sg[3][row][col];
  float co = ws->c[par][b2*HH + jj];
  float cn = sigm(fv)*co + sigm(iv)*tanhf(gv);
  float hn = sigm(ov)*tanhf(cn);
  int p2 = par ^ 1;
  ws->c[p2][b2*HH + jj] = cn;
  ws->h[p2][b2*HH + jj] = hn;
  bf16 hi = (bf16)hn;
  ws->h_hi[p2][b2*HH + jj] = hi;
  ws->h_lo[p2][b2*HH + jj] = (bf16)(hn - (float)hi);
}

extern "C" void kernel_launch(void* const* d_in, const int* in_sizes, int n_in,
                              void* d_out, int out_size, void* d_ws, size_t ws_size,
                              hipStream_t stream)
{
  const float* feat = (const float*)d_in[0];
  const int*   caps = (const int*)d_in[1];
  const float* emb  = (const float*)d_in[2];
  const float* Wih  = (const float*)d_in[3];
  const float* bih  = (const float*)d_in[4];
  const float* Whh  = (const float*)d_in[5];
  const float* bhh  = (const float*)d_in[6];
  const float* Wenc = (const float*)d_in[7];
  const float* benc = (const float*)d_in[8];
  const float* Wdec = (const float*)d_in[9];
  const float* bdec = (const float*)d_in[10];
  const float* Wfull= (const float*)d_in[11];
  const float* bfull= (const float*)d_in[12];
  const float* Winh = (const float*)d_in[13];
  const float* binh = (const float*)d_in[14];
  const float* Winc = (const float*)d_in[15];
  const float* binc = (const float*)d_in[16];
  const float* Wfcn = (const float*)d_in[17];
  const float* bfcn = (const float*)d_in[18];
  float* out = (float*)d_out;
  Wks* ws = (Wks*)d_ws;
  if (ws_size < sizeof(Wks)) return;

  // one-time fp32 -> bf16 conversions
  #define CVT(src, hi, lo, n) hipLaunchKernelGGL(k_cvt, dim3(((n)/4+255)/256), dim3(256), 0, stream, src, hi, lo, (n)/4)
  CVT(feat, ws->feat_hi, ws->feat_lo, BB*NN*CENC);
  CVT(Wih,  ws->Wih_hi,  ws->Wih_lo,  4*HH*(EE+CENC));
  CVT(Whh,  ws->Whh_hi,  ws->Whh_lo,  4*HH*HH);
  CVT(Wenc, ws->Wenc_hi, (bf16*)nullptr, AAT*CENC);
  CVT(Wfcn, ws->Wfcn_hi, (bf16*)nullptr, VV*HH);
  CVT(Winh, ws->Winh_hi, (bf16*)nullptr, HH*CENC);
  CVT(Winc, ws->Winc_hi, (bf16*)nullptr, HH*CENC);
  #undef CVT

  hipLaunchKernelGGL(k_mean, dim3(512), dim3(256), 0, stream, feat, ws);
  hipLaunchKernelGGL(k_init, dim3(16), dim3(256), 0, stream, ws, binh, binc);
  hipLaunchKernelGGL(k_att1, dim3(392), dim3(256), 0, stream, benc, ws);
  for (int t=0; t<NSTEP; t++){
    hipLaunchKernelGGL(k_step_a, dim3(221), dim3(256), 0, stream,
        t, t&1, 1, (t>0)?1:0, t-1, feat, Wdec, bdec, Wfull, bfull, bfcn, ws, out);
    hipLaunchKernelGGL(k_step_b, dim3(128), dim3(256), 0, stream,
        t, t&1, caps, emb, bih, bhh, ws);
  }
  // final pred for step s=24 from h parity 1 (written by k_step_b at t=24)
  hipLaunchKernelGGL(k_step_a, dim3(221), dim3(256), 0, stream,
      25, 1, 0, 1, 24, feat, Wdec, bdec, Wfull, bfull, bfcn, ws, out);
}

// Round 3
// 2318.373 us; speedup vs baseline: 1.6362x; 1.6362x over previous
//
#include <hip/hip_runtime.h>
#include <hip/hip_bf16.h>
#include <math.h>

typedef __bf16 bf16;
typedef __bf16 bf16x4 __attribute__((ext_vector_type(4)));
typedef __bf16 bf16x8 __attribute__((ext_vector_type(8)));
typedef float f32x4 __attribute__((ext_vector_type(4)));

#define BB 64
#define NN 49
#define CENC 2048
#define SS 26
#define NSTEP 25
#define VV 10000
#define EE 512
#define HH 512
#define AAT 512
#define ALPHA_OFF (BB*NSTEP*VV)   /* 16,000,000 */

// ~53 MiB workspace
struct Wks {
  float att1[BB*NN*AAT];          // fp32 loop-invariant attention projection
  float h[2][BB*HH];              // double-buffered fp32 LSTM state
  float c[2][BB*HH];
  bf16 h_hi[2][BB*HH];            // hi/lo split of h (MFMA A operand)
  bf16 h_lo[2][BB*HH];
  bf16 ctx_hi[BB*CENC];           // hi/lo split of attention context
  bf16 ctx_lo[BB*CENC];
  bf16 mean_hi[BB*CENC];
  bf16 mean_lo[BB*CENC];
  bf16 hist_hi[NSTEP*BB*HH];      // h history (row = s*64 + b) for final pred GEMM
  bf16 hist_lo[NSTEP*BB*HH];
  bf16 Wih_hi[4*HH*(EE+CENC)];
  bf16 Wih_lo[4*HH*(EE+CENC)];
  bf16 Whh_hi[4*HH*HH];
  bf16 Whh_lo[4*HH*HH];
  bf16 Wenc_hi[AAT*CENC];
  bf16 Wdec_hi[AAT*HH];
  bf16 Wfcn_hi[VV*HH];
  bf16 Winh_hi[HH*CENC];
  bf16 Winc_hi[HH*CENC];
};

__device__ inline bf16x8 ldb8(const bf16* p){ return *(const bf16x8*)p; }
__device__ inline f32x4 mfma16(bf16x8 a, bf16x8 b, f32x4 c){
  return __builtin_amdgcn_mfma_f32_16x16x32_bf16(a, b, c, 0, 0, 0);
}
__device__ inline float sigm(float x){ return 1.0f/(1.0f+expf(-x)); }

__device__ inline void split8(const float* p, bf16x8& hi, bf16x8& lo){
  float4 v0 = *(const float4*)p;
  float4 v1 = *(const float4*)(p+4);
  float v[8] = {v0.x,v0.y,v0.z,v0.w,v1.x,v1.y,v1.z,v1.w};
  #pragma unroll
  for (int j=0;j<8;j++){ bf16 h=(bf16)v[j]; hi[j]=h; lo[j]=(bf16)(v[j]-(float)h); }
}

// ---------------- fp32 -> bf16 hi (+ optional lo) convert --------------------------
__global__ __launch_bounds__(256) void k_cvt(const float* __restrict__ src,
    bf16* __restrict__ hi, bf16* __restrict__ lo, int n4){
  int i = blockIdx.x*256 + threadIdx.x;
  if (i >= n4) return;
  float4 v = ((const float4*)src)[i];
  float a[4] = {v.x, v.y, v.z, v.w};
  bf16x4 hv, lv;
  #pragma unroll
  for (int j=0;j<4;j++){ bf16 h=(bf16)a[j]; hv[j]=h; lv[j]=(bf16)(a[j]-(float)h); }
  *(bf16x4*)(hi + i*4) = hv;
  if (lo) *(bf16x4*)(lo + i*4) = lv;
}

// ---------------- mean over N=49 pixels, hi/lo split -------------------------------
__global__ __launch_bounds__(256) void k_mean(const float* __restrict__ feat, Wks* __restrict__ ws){
  int idx = blockIdx.x*256 + threadIdx.x;
  int b = idx >> 11, ch = idx & 2047;
  const float* p = feat + (size_t)b*NN*CENC + ch;
  float s = 0.f;
  #pragma unroll
  for (int n=0;n<NN;n++) s += p[n*CENC];
  s *= (1.0f/49.0f);
  bf16 hi = (bf16)s;
  ws->mean_hi[idx] = hi;
  ws->mean_lo[idx] = (bf16)(s - (float)hi);
}

// ---------------- h0/c0 init (MFMA, 2-term) ----------------------------------------
__global__ __launch_bounds__(256) void k_init(Wks* __restrict__ ws,
    const float* __restrict__ bh, const float* __restrict__ bc){
  int wid = threadIdx.x >> 6, lane = threadIdx.x & 63;
  int w = blockIdx.x*4 + wid;
  int mat = w >> 5, nt = w & 31;
  int lane15 = lane & 15, quad = lane >> 4, koff = quad*8;
  const bf16* Wm = mat ? ws->Winc_hi : ws->Winh_hi;
  const float* bm = mat ? bc : bh;
  int col = nt*16 + lane15;
  const bf16* brow = Wm + (size_t)col*CENC;
  f32x4 acc[4] = {};
  for (int kk=0; kk<CENC; kk+=32){
    bf16x8 bfr = ldb8(brow + kk + koff);
    #pragma unroll
    for (int t=0;t<4;t++){
      acc[t] = mfma16(ldb8(ws->mean_hi + (t*16+lane15)*CENC + kk + koff), bfr, acc[t]);
      acc[t] = mfma16(ldb8(ws->mean_lo + (t*16+lane15)*CENC + kk + koff), bfr, acc[t]);
    }
  }
  float bias = bm[col];
  #pragma unroll
  for (int t=0;t<4;t++){
    #pragma unroll
    for (int r=0;r<4;r++){
      int b = t*16 + quad*4 + r;
      float v = acc[t][r] + bias;
      if (mat == 0){
        ws->h[0][b*HH + col] = v;
        bf16 hi = (bf16)v;
        ws->h_hi[0][b*HH+col] = hi;
        ws->h_lo[0][b*HH+col] = (bf16)(v - (float)hi);
      } else {
        ws->c[0][b*HH + col] = v;
      }
    }
  }
}

// ---------------- att1 = features @ W_enc^T + b (split8 A, 2-term) -----------------
__global__ __launch_bounds__(256) void k_att1(const float* __restrict__ feat,
    const float* __restrict__ benc, Wks* __restrict__ ws){
  int wid = threadIdx.x>>6, lane = threadIdx.x&63;
  int w = blockIdx.x*4 + wid;                  // 196 m-tiles x 8 n-groups
  int mt = w >> 3, ng = w & 7;
  int lane15 = lane&15, quad = lane>>4, koff = quad*8;
  const float* arow = feat + (size_t)(mt*16 + lane15)*CENC;
  int a0 = ng*64;
  f32x4 acc[4] = {};
  for (int kk=0; kk<CENC; kk+=32){
    bf16x8 fh, fl;
    split8(arow + kk + koff, fh, fl);
    #pragma unroll
    for (int u=0;u<4;u++){
      bf16x8 wv = ldb8(ws->Wenc_hi + (size_t)(a0+u*16+lane15)*CENC + kk + koff);
      acc[u] = mfma16(fh, wv, acc[u]);
      acc[u] = mfma16(fl, wv, acc[u]);
    }
  }
  #pragma unroll
  for (int u=0;u<4;u++){
    int colb = a0 + u*16 + lane15;
    float bias = benc[colb];
    #pragma unroll
    for (int r=0;r<4;r++){
      int row = mt*16 + quad*4 + r;
      ws->att1[(size_t)row*AAT + colb] = acc[u][r] + bias;
    }
  }
}

// ---------------- per-step: attention only (64 blocks, one per batch) --------------
__global__ __launch_bounds__(256) void k_step_a(
    int t, int par, const float* __restrict__ feat,
    const float* __restrict__ bdec, const float* __restrict__ Wfull,
    const float* __restrict__ bfull,
    Wks* __restrict__ ws, float* __restrict__ out)
{
  int b = blockIdx.x;
  int tid = threadIdx.x;
  int wid = tid>>6, lane = tid&63;
  __shared__ float sh_h[512];
  __shared__ float sh_att2[512];
  __shared__ float sh_wf[512];
  __shared__ float sh_alpha[64];
  __shared__ float sh_e[64];
  {
    const float* hp = ws->h[par] + b*HH;
    sh_h[tid] = hp[tid]; sh_h[tid+256] = hp[tid+256];
    sh_wf[tid] = Wfull[tid]; sh_wf[tid+256] = Wfull[tid+256];
  }
  __syncthreads();
  // att2 = h @ Wdec^T : per-thread row dots (rows tid, tid+256), h broadcast from LDS
  {
    const bf16* r0 = ws->Wdec_hi + (size_t)tid*HH;
    const bf16* r1 = r0 + (size_t)256*HH;
    float a0=0.f, a1=0.f, a2=0.f, a3=0.f;   // 2 accumulators per row to break dep chain
    for (int kk=0; kk<HH; kk+=16){
      bf16x8 w0 = ldb8(r0+kk), w0b = ldb8(r0+kk+8);
      bf16x8 w1 = ldb8(r1+kk), w1b = ldb8(r1+kk+8);
      #pragma unroll
      for (int j=0;j<8;j++){
        float hv = sh_h[kk+j], hv2 = sh_h[kk+8+j];
        a0 += hv*(float)w0[j];  a2 += hv2*(float)w0b[j];
        a1 += hv*(float)w1[j];  a3 += hv2*(float)w1b[j];
      }
    }
    sh_att2[tid]     = a0 + a2 + bdec[tid];
    sh_att2[tid+256] = a1 + a3 + bdec[tid+256];
  }
  __syncthreads();
  // e[n] = relu(att1 + att2) . w_full + b_full
  for (int n = wid; n < NN; n += 4){
    const float* at1 = ws->att1 + (size_t)(b*NN + n)*AAT + lane*8;
    const float* a2p = sh_att2 + lane*8;
    const float* wfp = sh_wf + lane*8;
    float s = 0.f;
    #pragma unroll
    for (int j=0;j<8;j++){
      float v = at1[j] + a2p[j];
      v = fmaxf(v, 0.0f);
      s += v * wfp[j];
    }
    #pragma unroll
    for (int off=32; off; off>>=1) s += __shfl_xor(s, off, 64);
    if (lane==0) sh_e[n] = s + bfull[0];
  }
  __syncthreads();
  if (wid == 0){
    float e = (lane < NN) ? sh_e[lane] : -1e30f;
    float m = e;
    #pragma unroll
    for (int off=32; off; off>>=1) m = fmaxf(m, __shfl_xor(m, off, 64));
    float p = (lane < NN) ? expf(e - m) : 0.0f;
    float sum = p;
    #pragma unroll
    for (int off=32; off; off>>=1) sum += __shfl_xor(sum, off, 64);
    float al = p / sum;
    if (lane < NN){
      sh_alpha[lane] = al;
      out[ALPHA_OFF + (size_t)(b*NSTEP + t)*NN + lane] = al;
    }
  }
  __syncthreads();
  // context = sum_n alpha_n * feat[b,n,:]; hi/lo split
  int ch0 = tid*8;
  float acc[8] = {};
  for (int n=0;n<NN;n++){
    float al = sh_alpha[n];
    const float* fp = feat + (size_t)(b*NN+n)*CENC + ch0;
    float4 f0 = *(const float4*)fp;
    float4 f1 = *(const float4*)(fp+4);
    float fv[8] = {f0.x,f0.y,f0.z,f0.w,f1.x,f1.y,f1.z,f1.w};
    #pragma unroll
    for (int j=0;j<8;j++) acc[j] += al*fv[j];
  }
  #pragma unroll
  for (int j=0;j<8;j++){
    float v = acc[j];
    bf16 hi = (bf16)v;
    ws->ctx_hi[b*CENC + ch0 + j] = hi;
    ws->ctx_lo[b*CENC + ch0 + j] = (bf16)(v - (float)hi);
  }
}

// ---------------- per-step: gates GEMM, K-split x4 in-block (16 waves) -------------
__global__ __launch_bounds__(1024) void k_step_b(
    int s, int par,
    const int* __restrict__ caps, const float* __restrict__ emb,
    const float* __restrict__ bih, const float* __restrict__ bhh,
    Wks* __restrict__ ws)
{
  int tid = threadIdx.x;
  int w = tid>>6, lane = tid&63;
  int g = w & 3, kq = w >> 2;                  // gate, K-quarter
  int bt = blockIdx.x >> 5, jt = blockIdx.x & 31;
  int lane15 = lane&15, quad = lane>>4, koff = quad*8;
  int j = g*HH + jt*16 + lane15;
  const bf16* wih_hi = ws->Wih_hi + (size_t)j*(EE+CENC);
  const bf16* wih_lo = ws->Wih_lo + (size_t)j*(EE+CENC);
  const bf16* whh_hi = ws->Whh_hi + (size_t)j*HH;
  const bf16* whh_lo = ws->Whh_lo + (size_t)j*HH;
  int brow = bt*16 + lane15;
  int cap = caps[brow*SS + s];
  const float* aemb = emb + (size_t)cap*EE;
  const bf16* achi = ws->ctx_hi + brow*CENC;
  const bf16* aclo = ws->ctx_lo + brow*CENC;
  const bf16* ahhi = ws->h_hi[par] + brow*HH;
  const bf16* ahlo = ws->h_lo[par] + brow*HH;
  f32x4 acc = {};
  #pragma unroll 4
  for (int i=0;i<24;i++){
    int v = kq*768 + i*32;                     // virtual K in [0,3072)
    if (v < EE){                               // embedding columns of W_ih
      bf16x8 whi = ldb8(wih_hi + v + koff);
      bf16x8 wlo = ldb8(wih_lo + v + koff);
      bf16x8 ah, al; split8(aemb + v + koff, ah, al);
      acc = mfma16(ah, whi, acc);
      acc = mfma16(al, whi, acc);
      acc = mfma16(ah, wlo, acc);
    } else if (v < EE + CENC){                 // context columns of W_ih
      int k2 = v - EE;
      bf16x8 whi = ldb8(wih_hi + v + koff);
      bf16x8 wlo = ldb8(wih_lo + v + koff);
      bf16x8 ah = ldb8(achi + k2 + koff);
      acc = mfma16(ah, whi, acc);
      acc = mfma16(ldb8(aclo + k2 + koff), whi, acc);
      acc = mfma16(ah, wlo, acc);
    } else {                                   // recurrent h through W_hh
      int k2 = v - (EE + CENC);
      bf16x8 whi = ldb8(whh_hi + k2 + koff);
      bf16x8 wlo = ldb8(whh_lo + k2 + koff);
      bf16x8 ah = ldb8(ahhi + k2 + koff);
      acc = mfma16(ah, whi, acc);
      acc = mfma16(ldb8(ahlo + k2 + koff), whi, acc);
      acc = mfma16(ah, wlo, acc);
    }
  }
  __shared__ float sg[4][4][16][16];           // [kq][g][row][col]
  #pragma unroll
  for (int r=0;r<4;r++) sg[kq][g][quad*4+r][lane15] = acc[r];
  __syncthreads();
  if (tid < 256){
    int row = tid>>4, col = tid&15;
    int b2 = bt*16 + row, jj = jt*16 + col;
    int jg0 = jt*16 + col;
    float iv = sg[0][0][row][col]+sg[1][0][row][col]+sg[2][0][row][col]+sg[3][0][row][col] + bih[jg0]        + bhh[jg0];
    float fv = sg[0][1][row][col]+sg[1][1][row][col]+sg[2][1][row][col]+sg[3][1][row][col] + bih[HH+jg0]     + bhh[HH+jg0];
    float gv = sg[0][2][row][col]+sg[1][2][row][col]+sg[2][2][row][col]+sg[3][2][row][col] + bih[2*HH+jg0]   + bhh[2*HH+jg0];
    float ov = sg[0][3][row][col]+sg[1][3][row][col]+sg[2][3][row][col]+sg[3][3][row][col] + bih[3*HH+jg0]   + bhh[3*HH+jg0];
    float co = ws->c[par][b2*HH + jj];
    float cn = sigm(fv)*co + sigm(iv)*tanhf(gv);
    float hn = sigm(ov)*tanhf(cn);
    int p2 = par ^ 1;
    ws->c[p2][b2*HH + jj] = cn;
    ws->h[p2][b2*HH + jj] = hn;
    bf16 hi = (bf16)hn;
    bf16 lo = (bf16)(hn - (float)hi);
    ws->h_hi[p2][b2*HH + jj] = hi;
    ws->h_lo[p2][b2*HH + jj] = lo;
    ws->hist_hi[((size_t)s*BB + b2)*HH + jj] = hi;
    ws->hist_lo[((size_t)s*BB + b2)*HH + jj] = lo;
  }
}

// ---------------- final pred GEMM: [1600 x 10000] = hist @ Wfcn^T ------------------
__global__ __launch_bounds__(256) void k_pred(Wks* __restrict__ ws,
    const float* __restrict__ bfcn, float* __restrict__ out)
{
  int wid = threadIdx.x>>6, lane = threadIdx.x&63;
  int mt = blockIdx.y*4 + wid;                 // hist m-tile (64 rows each), valid < 25
  int nt = blockIdx.x;                         // vocab tile of 64
  if (mt >= NSTEP) return;
  int lane15 = lane&15, quad = lane>>4, koff = quad*8;
  int m0 = mt*64, n0 = nt*64;
  f32x4 acc[4][4] = {};                        // [n-subtile][m-subtile]
  for (int kk=0; kk<HH; kk+=32){
    bf16x8 a_hi[4], a_lo[4], bw[4];
    #pragma unroll
    for (int i=0;i<4;i++){
      a_hi[i] = ldb8(ws->hist_hi + (size_t)(m0+i*16+lane15)*HH + kk+koff);
      a_lo[i] = ldb8(ws->hist_lo + (size_t)(m0+i*16+lane15)*HH + kk+koff);
    }
    #pragma unroll
    for (int u=0;u<4;u++){
      int vc = n0 + u*16 + lane15; if (vc >= VV) vc = VV-1;
      bw[u] = ldb8(ws->Wfcn_hi + (size_t)vc*HH + kk+koff);
    }
    #pragma unroll
    for (int u=0;u<4;u++){
      #pragma unroll
      for (int i=0;i<4;i++){
        acc[u][i] = mfma16(a_hi[i], bw[u], acc[u][i]);
        acc[u][i] = mfma16(a_lo[i], bw[u], acc[u][i]);
      }
    }
  }
  #pragma unroll
  for (int u=0;u<4;u++){
    int vc = n0 + u*16 + lane15;
    if (vc < VV){
      float bias = bfcn[vc];
      #pragma unroll
      for (int i=0;i<4;i++){
        #pragma unroll
        for (int r=0;r<4;r++){
          int row = m0 + i*16 + quad*4 + r;    // hist row = s*64 + b
          int sstep = row >> 6, bidx = row & 63;
          out[(size_t)(bidx*NSTEP + sstep)*VV + vc] = acc[u][i][r] + bias;
        }
      }
    }
  }
}

extern "C" void kernel_launch(void* const* d_in, const int* in_sizes, int n_in,
                              void* d_out, int out_size, void* d_ws, size_t ws_size,
                              hipStream_t stream)
{
  const float* feat = (const float*)d_in[0];
  const int*   caps = (const int*)d_in[1];
  const float* emb  = (const float*)d_in[2];
  const float* Wih  = (const float*)d_in[3];
  const float* bih  = (const float*)d_in[4];
  const float* Whh  = (const float*)d_in[5];
  const float* bhh  = (const float*)d_in[6];
  const float* Wenc = (const float*)d_in[7];
  const float* benc = (const float*)d_in[8];
  const float* Wdec = (const float*)d_in[9];
  const float* bdec = (const float*)d_in[10];
  const float* Wfull= (const float*)d_in[11];
  const float* bfull= (const float*)d_in[12];
  const float* Winh = (const float*)d_in[13];
  const float* binh = (const float*)d_in[14];
  const float* Winc = (const float*)d_in[15];
  const float* binc = (const float*)d_in[16];
  const float* Wfcn = (const float*)d_in[17];
  const float* bfcn = (const float*)d_in[18];
  float* out = (float*)d_out;
  Wks* ws = (Wks*)d_ws;
  if (ws_size < sizeof(Wks)) return;

  #define CVT(src, hi, lo, n) hipLaunchKernelGGL(k_cvt, dim3(((n)/4+255)/256), dim3(256), 0, stream, src, hi, lo, (n)/4)
  CVT(Wih,  ws->Wih_hi,  ws->Wih_lo,  4*HH*(EE+CENC));
  CVT(Whh,  ws->Whh_hi,  ws->Whh_lo,  4*HH*HH);
  CVT(Wenc, ws->Wenc_hi, (bf16*)nullptr, AAT*CENC);
  CVT(Wdec, ws->Wdec_hi, (bf16*)nullptr, AAT*HH);
  CVT(Wfcn, ws->Wfcn_hi, (bf16*)nullptr, VV*HH);
  CVT(Winh, ws->Winh_hi, (bf16*)nullptr, HH*CENC);
  CVT(Winc, ws->Winc_hi, (bf16*)nullptr, HH*CENC);
  #undef CVT

  hipLaunchKernelGGL(k_mean, dim3(512), dim3(256), 0, stream, feat, ws);
  hipLaunchKernelGGL(k_init, dim3(16), dim3(256), 0, stream, ws, binh, binc);
  hipLaunchKernelGGL(k_att1, dim3(392), dim3(256), 0, stream, feat, benc, ws);
  for (int t=0; t<NSTEP; t++){
    hipLaunchKernelGGL(k_step_a, dim3(64), dim3(256), 0, stream,
        t, t&1, feat, bdec, Wfull, bfull, ws, out);
    hipLaunchKernelGGL(k_step_b, dim3(128), dim3(1024), 0, stream,
        t, t&1, caps, emb, bih, bhh, ws);
  }
  hipLaunchKernelGGL(k_pred, dim3(157, 7), dim3(256), 0, stream, ws, bfcn, out);
}

// Round 4
// 2148.264 us; speedup vs baseline: 1.7658x; 1.0792x over previous
//
#include <hip/hip_runtime.h>
#include <hip/hip_bf16.h>
#include <math.h>

typedef __bf16 bf16;
typedef __bf16 bf16x4 __attribute__((ext_vector_type(4)));
typedef __bf16 bf16x8 __attribute__((ext_vector_type(8)));
typedef float f32x4 __attribute__((ext_vector_type(4)));

#define BB 64
#define NN 49
#define CENC 2048
#define SS 26
#define NSTEP 25
#define VV 10000
#define EE 512
#define HH 512
#define AAT 512
#define ALPHA_OFF (BB*NSTEP*VV)

// T16 swizzled layout for MFMA operands: matrix M[R x K] (R%16==0, K%32==0)
// element (r,k) at sw[((rt*KC + kc)*64 + lane)*8 + j]
//   rt=r/16, kc=k/32, lane=((k%32)/8)*16 + (r%16), j=k%8, KC=K/32
// A wave's ldb8(sw + tile*512 + lane*8) is 1KB contiguous and delivers the exact
// fragment (row=lane&15, k=quad*8+j) both for A and B operands.

struct Wks {
  float att1[BB*NN*AAT];            // fp32 row-major
  float h[2][BB*HH];                // fp32 row-major state (att2 reads it)
  float c[2][BB*HH];
  bf16 h_hi[2][BB*HH];              // T16 (R=64,K=512,KC=16)
  bf16 h_lo[2][BB*HH];
  bf16 ctx_hi[BB*CENC];             // T16 (R=64,K=2048,KC=64)
  bf16 ctx_lo[BB*CENC];
  bf16 mean_hi[BB*CENC];            // T16 (R=64,K=2048)
  bf16 mean_lo[BB*CENC];
  bf16 xemb_hi[NSTEP*BB*EE];        // T16 (R=1600,K=512,KC=16), row=s*64+b
  bf16 xemb_lo[NSTEP*BB*EE];
  bf16 hist_hi[NSTEP*BB*HH];        // T16 (R=1600,K=512), row=s*64+b
  bf16 hist_lo[NSTEP*BB*HH];
  bf16 Wih_hi[4*HH*(EE+CENC)];      // T16 (R=2048,K=2560,KC=80)
  bf16 Wih_lo[4*HH*(EE+CENC)];
  bf16 Whh_hi[4*HH*HH];             // T16 (R=2048,K=512,KC=16)
  bf16 Whh_lo[4*HH*HH];
  bf16 Wenc_hi[AAT*CENC];           // T16 (R=512,K=2048,KC=64)
  bf16 Wdec_hi[AAT*HH];             // ROW-MAJOR (per-wave row dots)
  bf16 Wfcn_hi[10048*HH];           // T16 (R=10000 pad 10048,K=512,KC=16)
  bf16 Winh_hi[HH*CENC];            // T16 (R=512,K=2048)
  bf16 Winc_hi[HH*CENC];
};

__device__ inline bf16x8 ldb8(const bf16* p){ return *(const bf16x8*)p; }
__device__ inline f32x4 mfma16(bf16x8 a, bf16x8 b, f32x4 c){
  return __builtin_amdgcn_mfma_f32_16x16x32_bf16(a, b, c, 0, 0, 0);
}
__device__ inline float sigm(float x){ return 1.0f/(1.0f+expf(-x)); }

__device__ inline void split8(const float* p, bf16x8& hi, bf16x8& lo){
  float4 v0 = *(const float4*)p;
  float4 v1 = *(const float4*)(p+4);
  float v[8] = {v0.x,v0.y,v0.z,v0.w,v1.x,v1.y,v1.z,v1.w};
  #pragma unroll
  for (int j=0;j<8;j++){ bf16 h=(bf16)v[j]; hi[j]=h; lo[j]=(bf16)(v[j]-(float)h); }
}

// ---------------- plain fp32 -> bf16 hi convert (row-major, Wdec only) -------------
__global__ __launch_bounds__(256) void k_cvt(const float* __restrict__ src,
    bf16* __restrict__ hi, int n4){
  int i = blockIdx.x*256 + threadIdx.x;
  if (i >= n4) return;
  float4 v = ((const float4*)src)[i];
  float a[4] = {v.x, v.y, v.z, v.w};
  bf16x4 hv;
  #pragma unroll
  for (int j=0;j<4;j++) hv[j] = (bf16)a[j];
  *(bf16x4*)(hi + i*4) = hv;
}

// ---------------- fp32 row-major -> T16 swizzle (hi + optional lo) -----------------
__global__ __launch_bounds__(256) void k_cvt_sw(const float* __restrict__ src,
    bf16* __restrict__ hi, bf16* __restrict__ lo, int R, int K, int ntile){
  int g = blockIdx.x*256 + threadIdx.x;
  if (g >= ntile*64) return;
  int tile = g>>6, lane = g&63;
  int KC = K>>5;
  int rt = tile/KC, kc = tile - rt*KC;
  int r = rt*16 + (lane&15);
  if (r >= R) r = R-1;                       // pad rows duplicate last row
  int k = kc*32 + (lane>>4)*8;
  bf16x8 hv, lv;
  split8(src + (size_t)r*K + k, hv, lv);
  *(bf16x8*)(hi + (size_t)g*8) = hv;
  if (lo) *(bf16x8*)(lo + (size_t)g*8) = lv;
}

// ---------------- gather caption embeddings -> T16 hi/lo ---------------------------
__global__ __launch_bounds__(256) void k_emb(const int* __restrict__ caps,
    const float* __restrict__ emb, Wks* __restrict__ ws){
  int g = blockIdx.x*256 + threadIdx.x;      // 1600 tiles * 64 lanes
  if (g >= 1600*64) return;
  int tile = g>>6, lane = g&63;
  int rt = tile>>4, kc = tile&15;            // KC=16
  int r = rt*16 + (lane&15);
  int s = r>>6, b = r&63;
  int k = kc*32 + (lane>>4)*8;
  int cap = caps[b*SS + s];
  bf16x8 hv, lv;
  split8(emb + (size_t)cap*EE + k, hv, lv);
  *(bf16x8*)(ws->xemb_hi + (size_t)g*8) = hv;
  *(bf16x8*)(ws->xemb_lo + (size_t)g*8) = lv;
}

// ---------------- mean over N=49 pixels -> T16 hi/lo -------------------------------
__global__ __launch_bounds__(256) void k_mean(const float* __restrict__ feat, Wks* __restrict__ ws){
  int idx = blockIdx.x*256 + threadIdx.x;    // 64*2048
  int b = idx >> 11, ch = idx & 2047;
  const float* p = feat + (size_t)b*NN*CENC + ch;
  float s = 0.f;
  #pragma unroll
  for (int n=0;n<NN;n++) s += p[n*CENC];
  s *= (1.0f/49.0f);
  bf16 hi = (bf16)s;
  int off = (((b>>4)*64 + (ch>>5))*64 + ((ch&31)>>3)*16 + (b&15))*8 + (ch&7);
  ws->mean_hi[off] = hi;
  ws->mean_lo[off] = (bf16)(s - (float)hi);
}

// ---------------- h0/c0 init (T16 operands) ----------------------------------------
__global__ __launch_bounds__(256) void k_init(Wks* __restrict__ ws,
    const float* __restrict__ bh, const float* __restrict__ bc){
  int wid = threadIdx.x >> 6, lane = threadIdx.x & 63;
  int w = blockIdx.x*4 + wid;                // 0..63
  int mat = w >> 5, nt = w & 31;
  int lane15 = lane & 15, quad = lane >> 4;
  const bf16* Wm = mat ? ws->Winc_hi : ws->Winh_hi;
  const float* bm = mat ? bc : bh;
  int col = nt*16 + lane15;
  f32x4 acc[4] = {};
  for (int kc=0; kc<64; kc++){
    bf16x8 bfr = ldb8(Wm + (((size_t)nt*64 + kc)*64 + lane)*8);
    #pragma unroll
    for (int t=0;t<4;t++){
      acc[t] = mfma16(ldb8(ws->mean_hi + (((size_t)t*64 + kc)*64 + lane)*8), bfr, acc[t]);
      acc[t] = mfma16(ldb8(ws->mean_lo + (((size_t)t*64 + kc)*64 + lane)*8), bfr, acc[t]);
    }
  }
  float bias = bm[col];
  #pragma unroll
  for (int t=0;t<4;t++){
    #pragma unroll
    for (int r=0;r<4;r++){
      int b = t*16 + quad*4 + r;
      float v = acc[t][r] + bias;
      if (mat == 0){
        ws->h[0][b*HH + col] = v;
        bf16 hi = (bf16)v;
        int off = (((b>>4)*16 + (col>>5))*64 + ((col&31)>>3)*16 + (b&15))*8 + (col&7);
        ws->h_hi[0][off] = hi;
        ws->h_lo[0][off] = (bf16)(v - (float)hi);
      } else {
        ws->c[0][b*HH + col] = v;
      }
    }
  }
}

// ---------------- att1 = features @ W_enc^T + b (A split8, B T16) ------------------
__global__ __launch_bounds__(256) void k_att1(const float* __restrict__ feat,
    const float* __restrict__ benc, Wks* __restrict__ ws){
  int wid = threadIdx.x>>6, lane = threadIdx.x&63;
  int w = blockIdx.x*4 + wid;                // 196 m-tiles x 8 n-groups
  int mt = w >> 3, ng = w & 7;
  int lane15 = lane&15, quad = lane>>4, koff = quad*8;
  const float* arow = feat + (size_t)(mt*16 + lane15)*CENC;
  f32x4 acc[4] = {};
  for (int kc=0; kc<64; kc++){
    bf16x8 fh, fl;
    split8(arow + kc*32 + koff, fh, fl);
    #pragma unroll
    for (int u=0;u<4;u++){
      bf16x8 wv = ldb8(ws->Wenc_hi + (((size_t)(ng*4+u)*64 + kc)*64 + lane)*8);
      acc[u] = mfma16(fh, wv, acc[u]);
      acc[u] = mfma16(fl, wv, acc[u]);
    }
  }
  #pragma unroll
  for (int u=0;u<4;u++){
    int colb = ng*64 + u*16 + lane15;
    float bias = benc[colb];
    #pragma unroll
    for (int r=0;r<4;r++){
      int row = mt*16 + quad*4 + r;
      ws->att1[(size_t)row*AAT + colb] = acc[u][r] + bias;
    }
  }
}

// ---------------- per-step: attention (64 blocks, one per batch) -------------------
__global__ __launch_bounds__(256) void k_step_a(
    int t, int par, const float* __restrict__ feat,
    const float* __restrict__ bdec, const float* __restrict__ Wfull,
    const float* __restrict__ bfull,
    Wks* __restrict__ ws, float* __restrict__ out)
{
  int b = blockIdx.x;
  int tid = threadIdx.x;
  int wid = tid>>6, lane = tid&63;
  __shared__ float sh_att2[512];
  __shared__ float sh_wf[512];
  __shared__ float sh_alpha[64];
  __shared__ float sh_e[64];
  sh_wf[tid] = Wfull[tid]; sh_wf[tid+256] = Wfull[tid+256];
  // h fragment: lane holds h[b, lane*8 .. +8] (fp32, coalesced 32B/lane)
  float h8[8];
  {
    const float* hp = ws->h[par] + b*HH + lane*8;
    #pragma unroll
    for (int j=0;j<8;j++) h8[j] = hp[j];
  }
  // att2: per-wave row dots over row-major bf16 Wdec (1KB/row, coalesced)
  {
    const bf16* wd = ws->Wdec_hi + (size_t)wid*128*HH + lane*8;
    #pragma unroll 2
    for (int r=0;r<128;r+=2){
      bf16x8 w0 = ldb8(wd + (size_t)r*HH);
      bf16x8 w1 = ldb8(wd + (size_t)(r+1)*HH);
      float s0=0.f, s1=0.f;
      #pragma unroll
      for (int j=0;j<8;j++){ s0 += (float)w0[j]*h8[j]; s1 += (float)w1[j]*h8[j]; }
      #pragma unroll
      for (int off=32; off; off>>=1){ s0 += __shfl_xor(s0,off,64); s1 += __shfl_xor(s1,off,64); }
      if (lane==0){
        int a0 = wid*128 + r;
        sh_att2[a0]   = s0 + bdec[a0];
        sh_att2[a0+1] = s1 + bdec[a0+1];
      }
    }
  }
  __syncthreads();
  // e[n] = relu(att1 + att2) . w_full + b_full
  for (int n = wid; n < NN; n += 4){
    const float* at1 = ws->att1 + (size_t)(b*NN + n)*AAT + lane*8;
    const float* a2p = sh_att2 + lane*8;
    const float* wfp = sh_wf + lane*8;
    float s = 0.f;
    #pragma unroll
    for (int j=0;j<8;j++){
      float v = at1[j] + a2p[j];
      v = fmaxf(v, 0.0f);
      s += v * wfp[j];
    }
    #pragma unroll
    for (int off=32; off; off>>=1) s += __shfl_xor(s, off, 64);
    if (lane==0) sh_e[n] = s + bfull[0];
  }
  __syncthreads();
  if (wid == 0){
    float e = (lane < NN) ? sh_e[lane] : -1e30f;
    float m = e;
    #pragma unroll
    for (int off=32; off; off>>=1) m = fmaxf(m, __shfl_xor(m, off, 64));
    float p = (lane < NN) ? expf(e - m) : 0.0f;
    float sum = p;
    #pragma unroll
    for (int off=32; off; off>>=1) sum += __shfl_xor(sum, off, 64);
    float al = p / sum;
    if (lane < NN){
      sh_alpha[lane] = al;
      out[ALPHA_OFF + (size_t)(b*NSTEP + t)*NN + lane] = al;
    }
  }
  __syncthreads();
  // context = sum_n alpha_n * feat[b,n,:]; write T16 hi/lo (16B store per thread)
  int ch0 = tid*8;
  float acc[8] = {};
  for (int n=0;n<NN;n++){
    float al = sh_alpha[n];
    const float* fp = feat + (size_t)(b*NN+n)*CENC + ch0;
    float4 f0 = *(const float4*)fp;
    float4 f1 = *(const float4*)(fp+4);
    float fv[8] = {f0.x,f0.y,f0.z,f0.w,f1.x,f1.y,f1.z,f1.w};
    #pragma unroll
    for (int j=0;j<8;j++) acc[j] += al*fv[j];
  }
  bf16x8 hv, lv;
  #pragma unroll
  for (int j=0;j<8;j++){
    bf16 hi = (bf16)acc[j];
    hv[j] = hi; lv[j] = (bf16)(acc[j] - (float)hi);
  }
  int off = (((b>>4)*64 + (ch0>>5))*64 + ((ch0&31)>>3)*16 + (b&15))*8;
  *(bf16x8*)(ws->ctx_hi + off) = hv;
  *(bf16x8*)(ws->ctx_lo + off) = lv;
}

// ---------------- per-step: gates GEMM (T16 operands, K-split x4) ------------------
__global__ __launch_bounds__(1024) void k_step_b(
    int s, int par,
    const float* __restrict__ bih, const float* __restrict__ bhh,
    Wks* __restrict__ ws)
{
  int tid = threadIdx.x;
  int w = tid>>6, lane = tid&63;
  int g = w & 3, kq = w >> 2;                // gate, K-quarter
  int bt = blockIdx.x >> 5, jt = blockIdx.x & 31;
  int lane15 = lane&15, quad = lane>>4;
  int wrt = g*32 + jt;                       // row-tile in 2048-row weights
  int v0 = kq*768, v1 = v0 + 768;            // virtual K in [0,3072)
  f32x4 acc = {};
  // emb section: v in [v0, min(v1,512))
  {
    int lo_ = v0, hi_ = v1 < EE ? v1 : EE;
    int nch = (hi_ - lo_) >> 5;
    if (nch > 0){
      int kc = lo_ >> 5;
      const bf16* pah = ws->xemb_hi + (((size_t)(s*4+bt)*16 + kc)*64 + lane)*8;
      const bf16* pal = ws->xemb_lo + (((size_t)(s*4+bt)*16 + kc)*64 + lane)*8;
      const bf16* pwh = ws->Wih_hi + (((size_t)wrt*80 + kc)*64 + lane)*8;
      const bf16* pwl = ws->Wih_lo + (((size_t)wrt*80 + kc)*64 + lane)*8;
      #pragma unroll 4
      for (int i=0;i<nch;i++){
        bf16x8 ah=ldb8(pah), al=ldb8(pal), wh=ldb8(pwh), wl=ldb8(pwl);
        acc = mfma16(ah, wh, acc);
        acc = mfma16(al, wh, acc);
        acc = mfma16(ah, wl, acc);
        pah += 512; pal += 512; pwh += 512; pwl += 512;
      }
    }
  }
  // ctx section: v in [max(v0,512), min(v1,2560))
  {
    int lo_ = v0 > EE ? v0 : EE;
    int hi_ = v1 < (EE+CENC) ? v1 : (EE+CENC);
    int nch = (hi_ - lo_) >> 5;
    if (nch > 0){
      int kc = lo_ >> 5;                     // Wih kc
      int kc2 = (lo_ - EE) >> 5;             // ctx kc
      const bf16* pah = ws->ctx_hi + (((size_t)bt*64 + kc2)*64 + lane)*8;
      const bf16* pal = ws->ctx_lo + (((size_t)bt*64 + kc2)*64 + lane)*8;
      const bf16* pwh = ws->Wih_hi + (((size_t)wrt*80 + kc)*64 + lane)*8;
      const bf16* pwl = ws->Wih_lo + (((size_t)wrt*80 + kc)*64 + lane)*8;
      #pragma unroll 4
      for (int i=0;i<nch;i++){
        bf16x8 ah=ldb8(pah), al=ldb8(pal), wh=ldb8(pwh), wl=ldb8(pwl);
        acc = mfma16(ah, wh, acc);
        acc = mfma16(al, wh, acc);
        acc = mfma16(ah, wl, acc);
        pah += 512; pal += 512; pwh += 512; pwl += 512;
      }
    }
  }
  // h section: v in [max(v0,2560), v1)
  {
    int lo_ = v0 > (EE+CENC) ? v0 : (EE+CENC);
    int nch = (v1 - lo_) >> 5;
    if (nch > 0){
      int kc3 = (lo_ - (EE+CENC)) >> 5;
      const bf16* pah = ws->h_hi[par] + (((size_t)bt*16 + kc3)*64 + lane)*8;
      const bf16* pal = ws->h_lo[par] + (((size_t)bt*16 + kc3)*64 + lane)*8;
      const bf16* pwh = ws->Whh_hi + (((size_t)wrt*16 + kc3)*64 + lane)*8;
      const bf16* pwl = ws->Whh_lo + (((size_t)wrt*16 + kc3)*64 + lane)*8;
      #pragma unroll 4
      for (int i=0;i<nch;i++){
        bf16x8 ah=ldb8(pah), al=ldb8(pal), wh=ldb8(pwh), wl=ldb8(pwl);
        acc = mfma16(ah, wh, acc);
        acc = mfma16(al, wh, acc);
        acc = mfma16(ah, wl, acc);
        pah += 512; pal += 512; pwh += 512; pwl += 512;
      }
    }
  }
  __shared__ float sg[4][4][16][16];         // [kq][g][row][col]
  #pragma unroll
  for (int r=0;r<4;r++) sg[kq][g][quad*4+r][lane15] = acc[r];
  __syncthreads();
  if (tid < 256){
    int row = tid>>4, col = tid&15;
    int b2 = bt*16 + row, jj = jt*16 + col;
    int jg0 = jt*16 + col;
    float iv = sg[0][0][row][col]+sg[1][0][row][col]+sg[2][0][row][col]+sg[3][0][row][col] + bih[jg0]      + bhh[jg0];
    float fv = sg[0][1][row][col]+sg[1][1][row][col]+sg[2][1][row][col]+sg[3][1][row][col] + bih[HH+jg0]   + bhh[HH+jg0];
    float gv = sg[0][2][row][col]+sg[1][2][row][col]+sg[2][2][row][col]+sg[3][2][row][col] + bih[2*HH+jg0] + bhh[2*HH+jg0];
    float ov = sg[0][3][row][col]+sg[1][3][row][col]+sg[2][3][row][col]+sg[3][3][row][col] + bih[3*HH+jg0] + bhh[3*HH+jg0];
    float co = ws->c[par][b2*HH + jj];
    float cn = sigm(fv)*co + sigm(iv)*tanhf(gv);
    float hn = sigm(ov)*tanhf(cn);
    int p2 = par ^ 1;
    ws->c[p2][b2*HH + jj] = cn;
    ws->h[p2][b2*HH + jj] = hn;
    bf16 hi = (bf16)hn;
    bf16 lo = (bf16)(hn - (float)hi);
    // T16 offsets: h (R=64) and hist (R=1600, row=s*64+b2)
    int kc = jj>>5, lane_w = ((jj&31)>>3)*16 + (b2&15), j8 = jj&7;
    int offh = (((b2>>4)*16 + kc)*64 + lane_w)*8 + j8;
    ws->h_hi[p2][offh] = hi;
    ws->h_lo[p2][offh] = lo;
    int offhist = ((((size_t)s*4 + (b2>>4))*16 + kc)*64 + lane_w)*8 + j8;
    ws->hist_hi[offhist] = hi;
    ws->hist_lo[offhist] = lo;
  }
}

// ---------------- final pred GEMM: [1600 x 10000] = hist @ Wfcn^T (T16) ------------
__global__ __launch_bounds__(256) void k_pred(Wks* __restrict__ ws,
    const float* __restrict__ bfcn, float* __restrict__ out)
{
  int wid = threadIdx.x>>6, lane = threadIdx.x&63;
  int mt = blockIdx.y*4 + wid;               // 64-row hist group, valid < 25
  int nt = blockIdx.x;                       // 64-col vocab group (157)
  if (mt >= NSTEP) return;
  int lane15 = lane&15, quad = lane>>4;
  int n0 = nt*64;
  f32x4 acc[4][4] = {};                      // [n-subtile][m-subtile]
  for (int kc=0; kc<16; kc++){
    bf16x8 a_hi[4], a_lo[4], bw[4];
    #pragma unroll
    for (int i=0;i<4;i++){
      a_hi[i] = ldb8(ws->hist_hi + (((size_t)(mt*4+i)*16 + kc)*64 + lane)*8);
      a_lo[i] = ldb8(ws->hist_lo + (((size_t)(mt*4+i)*16 + kc)*64 + lane)*8);
    }
    #pragma unroll
    for (int u=0;u<4;u++)
      bw[u] = ldb8(ws->Wfcn_hi + (((size_t)(nt*4+u)*16 + kc)*64 + lane)*8);
    #pragma unroll
    for (int u=0;u<4;u++){
      #pragma unroll
      for (int i=0;i<4;i++){
        acc[u][i] = mfma16(a_hi[i], bw[u], acc[u][i]);
        acc[u][i] = mfma16(a_lo[i], bw[u], acc[u][i]);
      }
    }
  }
  #pragma unroll
  for (int u=0;u<4;u++){
    int vc = n0 + u*16 + lane15;
    if (vc < VV){
      float bias = bfcn[vc];
      #pragma unroll
      for (int i=0;i<4;i++){
        #pragma unroll
        for (int r=0;r<4;r++){
          int row = mt*64 + i*16 + quad*4 + r;   // row = s*64 + b
          int sstep = row >> 6, bidx = row & 63;
          out[(size_t)(bidx*NSTEP + sstep)*VV + vc] = acc[u][i][r] + bias;
        }
      }
    }
  }
}

extern "C" void kernel_launch(void* const* d_in, const int* in_sizes, int n_in,
                              void* d_out, int out_size, void* d_ws, size_t ws_size,
                              hipStream_t stream)
{
  const float* feat = (const float*)d_in[0];
  const int*   caps = (const int*)d_in[1];
  const float* emb  = (const float*)d_in[2];
  const float* Wih  = (const float*)d_in[3];
  const float* bih  = (const float*)d_in[4];
  const float* Whh  = (const float*)d_in[5];
  const float* bhh  = (const float*)d_in[6];
  const float* Wenc = (const float*)d_in[7];
  const float* benc = (const float*)d_in[8];
  const float* Wdec = (const float*)d_in[9];
  const float* bdec = (const float*)d_in[10];
  const float* Wfull= (const float*)d_in[11];
  const float* bfull= (const float*)d_in[12];
  const float* Winh = (const float*)d_in[13];
  const float* binh = (const float*)d_in[14];
  const float* Winc = (const float*)d_in[15];
  const float* binc = (const float*)d_in[16];
  const float* Wfcn = (const float*)d_in[17];
  const float* bfcn = (const float*)d_in[18];
  float* out = (float*)d_out;
  Wks* ws = (Wks*)d_ws;
  if (ws_size < sizeof(Wks)) return;

  // one-time weight swizzles (T16)
  #define SW(src, hi, lo, R, K) do { int nt_ = ((R+15)/16)*((K)/32); \
    hipLaunchKernelGGL(k_cvt_sw, dim3((nt_*64+255)/256), dim3(256), 0, stream, \
        src, hi, lo, R, K, nt_); } while(0)
  SW(Wih,  ws->Wih_hi,  ws->Wih_lo,  2048, 2560);
  SW(Whh,  ws->Whh_hi,  ws->Whh_lo,  2048, 512);
  SW(Wenc, ws->Wenc_hi, (bf16*)nullptr, 512, 2048);
  SW(Wfcn, ws->Wfcn_hi, (bf16*)nullptr, 10000, 512);   // pads to 10048 rows
  SW(Winh, ws->Winh_hi, (bf16*)nullptr, 512, 2048);
  SW(Winc, ws->Winc_hi, (bf16*)nullptr, 512, 2048);
  #undef SW
  hipLaunchKernelGGL(k_cvt, dim3((AAT*HH/4+255)/256), dim3(256), 0, stream, Wdec, ws->Wdec_hi, AAT*HH/4);
  hipLaunchKernelGGL(k_emb, dim3(400), dim3(256), 0, stream, caps, emb, ws);
  hipLaunchKernelGGL(k_mean, dim3(512), dim3(256), 0, stream, feat, ws);
  hipLaunchKernelGGL(k_init, dim3(16), dim3(256), 0, stream, ws, binh, binc);
  hipLaunchKernelGGL(k_att1, dim3(392), dim3(256), 0, stream, feat, benc, ws);
  for (int t=0; t<NSTEP; t++){
    hipLaunchKernelGGL(k_step_a, dim3(64), dim3(256), 0, stream,
        t, t&1, feat, bdec, Wfull, bfull, ws, out);
    hipLaunchKernelGGL(k_step_b, dim3(128), dim3(1024), 0, stream,
        t, t&1, bih, bhh, ws);
  }
  hipLaunchKernelGGL(k_pred, dim3(157, 7), dim3(256), 0, stream, ws, bfcn, out);
}